// Round 4
// baseline (586.942 us; speedup 1.0000x reference)
//
#include <hip/hip_runtime.h>

typedef _Float16 half8 __attribute__((ext_vector_type(8)));
typedef float floatx4 __attribute__((ext_vector_type(4)));

#define LBF 2304   // Lb == Lf
#define K1  1152
#define LDK2 2304  // worst-case compacted stride (Kc can be up to 2304)

__device__ __forceinline__ void gll16(const _Float16* g, _Float16* l) {
    __builtin_amdgcn_global_load_lds((const __attribute__((address_space(1))) void*)g,
                                     (__attribute__((address_space(3))) void*)l, 16, 0, 0);
}

// ---------------- prep: fp patches (foreground, downsampled, 3x3, pad 1) ------
__global__ void prep_fp(const float* __restrict__ f, _Float16* __restrict__ fp) {
    int k = blockIdx.x * 128 + threadIdx.x;   // [0,1152)
    int p = blockIdx.y;                       // [0,2304)
    int b = blockIdx.z;
    int c = k / 9, r = k % 9, u = r / 3, v = r % 3;
    int pi = p / 48, pj = p % 48;
    int y = pi - 1 + u, x = pj - 1 + v;
    float val = 0.f;
    if ((unsigned)y < 48u && (unsigned)x < 48u)
        val = f[(((long)b * 128 + c) * 96 + 2 * y) * 96 + 2 * x];
    fp[((long)b * LBF + p) * K1 + k] = (_Float16)val;
}

// ---------------- prep: wn normalized background patches ----------------------
__global__ void prep_wn(const float* __restrict__ bsrc, _Float16* __restrict__ wn) {
    int p = blockIdx.x, b = blockIdx.y;
    int tid = threadIdx.x;  // 128 threads, 9 elems each
    int pi = p / 48, pj = p % 48;
    float w[9];
    float ss = 0.f;
#pragma unroll
    for (int t = 0; t < 9; t++) {
        int k = tid + t * 128;
        int c = k / 9, r = k % 9, u = r / 3, v = r % 3;
        int y = pi - 1 + u, x = pj - 1 + v;
        float val = 0.f;
        if ((unsigned)y < 48u && (unsigned)x < 48u)
            val = bsrc[(((long)b * 128 + c) * 96 + 2 * y) * 96 + 2 * x];
        w[t] = val;
        ss += val * val;
    }
    for (int m = 32; m; m >>= 1) ss += __shfl_xor(ss, m);
    __shared__ float sh[2];
    if ((tid & 63) == 0) sh[tid >> 6] = ss;
    __syncthreads();
    float denom = sqrtf(sh[0] + sh[1] + 0.1152f);  // sum(w^2 + ESC)
    float inv = 1.f / denom;
#pragma unroll
    for (int t = 0; t < 9; t++) {
        int k = tid + t * 128;
        wn[((long)b * LBF + p) * K1 + k] = (_Float16)(w[t] * inv);
    }
}

// ---------------- prep: mm flags from mask ------------------------------------
__global__ void prep_mm(const float* __restrict__ mask, float* __restrict__ mm) {
    int p = blockIdx.x * 256 + threadIdx.x;
    if (p >= LBF) return;
    int pi = p / 48, pj = p % 48;
    float s = 0.f;
#pragma unroll
    for (int u = 0; u < 3; u++)
#pragma unroll
        for (int v = 0; v < 3; v++) {
            int y = pi - 1 + u, x = pj - 1 + v;
            if ((unsigned)y < 48u && (unsigned)x < 48u)
                s += mask[(8 * y) * 384 + 8 * x];
        }
    mm[p] = (s == 0.f) ? 1.f : 0.f;
}

// ---------------- scan: exclusive prefix of mm -> pos[], kinfo ----------------
__global__ void scan_mm(const float* __restrict__ mmv, int* __restrict__ pos,
                        int* __restrict__ kinfo) {
    int tid = threadIdx.x;
    int loc[9]; int s = 0;
#pragma unroll
    for (int t = 0; t < 9; t++) {
        int m = (mmv[tid * 9 + t] != 0.f);
        loc[t] = s; s += m;
    }
    __shared__ int sh[256];
    sh[tid] = s; __syncthreads();
    for (int off = 1; off < 256; off <<= 1) {
        int v = (tid >= off) ? sh[tid - off] : 0;
        __syncthreads();
        sh[tid] += v;
        __syncthreads();
    }
    int excl = sh[tid] - s;
#pragma unroll
    for (int t = 0; t < 9; t++) pos[tid * 9 + t] = excl + loc[t];
    if (tid == 255) {
        int Kc = excl + s;
        kinfo[0] = Kc;
        kinfo[1] = (Kc + 63) & ~63;
        kinfo[2] = K1;
    }
}

// ---------------- prep: compacted Wt ------------------------------------------
__global__ void prep_wtc(const float* __restrict__ bsrc, const float* __restrict__ mmv,
                         const int* __restrict__ pos, _Float16* __restrict__ wtc) {
    int p = blockIdx.x * 256 + threadIdx.x;   // [0,2304)
    int n = blockIdx.y;                       // [0,2048)
    int b = blockIdx.z;
    if (mmv[p] == 0.f) return;
    int c = n >> 4, u = (n >> 2) & 3, v = n & 3;
    int pi = p / 48, pj = p % 48;
    int y = 2 * pi - 1 + u, x = 2 * pj - 1 + v;
    float val = 0.f;
    if ((unsigned)y < 96u && (unsigned)x < 96u)
        val = bsrc[(((long)b * 128 + c) * 96 + y) * 96 + x];
    wtc[((long)b * 2048 + n) * LDK2 + pos[p]] = (_Float16)val;
}

// ---------------- zero the pad columns [Kc, Kpad) ------------------------------
__global__ void pad_zero(_Float16* __restrict__ buf, const int* __restrict__ kinfo) {
    int row = blockIdx.x;                  // flattened (batch*rows)
    int col = kinfo[0] + threadIdx.x;
    if (col < kinfo[1]) buf[(long)row * LDK2 + col] = (_Float16)0.f;
}

// ---------------- NT GEMM, BK=64: C[M,N] = A[M,K] * B[N,K]^T ------------------
__global__ __launch_bounds__(256)
void gemm_nt64(const _Float16* __restrict__ A, const _Float16* __restrict__ B,
               float* __restrict__ C, int M, int N, int ldk,
               const int* __restrict__ Kptr, long sA, long sB, long sC) {
    A += blockIdx.z * sA; B += blockIdx.z * sB; C += blockIdx.z * sC;
    const int K = Kptr[0];
    const int tid = threadIdx.x;
    const int lane = tid & 63, wave = tid >> 6;
    const int wr = wave >> 1, wc = wave & 1;
    const int m0 = blockIdx.y * 128, n0 = blockIdx.x * 128;

    __shared__ _Float16 lA[128 * 64];   // 128 rows x 128 B, no pad
    __shared__ _Float16 lB[128 * 64];

    floatx4 acc[4][4] = {};

    const int lm = lane & 15, q = lane >> 4;
    const int pcp = (q ^ (lm & 7)) * 8;      // substep-0 phys offset (halves)

    const int srow8 = lane >> 3;
    const int gc = ((lane & 7) ^ srow8) * 8;  // global halves offset
    const _Float16* gA[4]; const _Float16* gB[4];
    _Float16* dA[4]; _Float16* dB[4];
#pragma unroll
    for (int c = 0; c < 4; c++) {
        int r = (wave * 4 + c) * 8 + srow8;
        gA[c] = A + (long)(m0 + r) * ldk + gc;
        gB[c] = B + (long)(n0 + r) * ldk + gc;
        dA[c] = &lA[(wave * 4 + c) * 512];
        dB[c] = &lB[(wave * 4 + c) * 512];
    }

    for (int k0 = 0; k0 < K; k0 += 64) {
        __syncthreads();
#pragma unroll
        for (int c = 0; c < 4; c++) gll16(gA[c] + k0, dA[c]);
#pragma unroll
        for (int c = 0; c < 4; c++) gll16(gB[c] + k0, dB[c]);
        __syncthreads();
        half8 af[4], bf[4];
#pragma unroll
        for (int t = 0; t < 4; t++) {
            af[t] = *(const half8*)&lA[(wr * 64 + t * 16 + lm) * 64 + pcp];
            bf[t] = *(const half8*)&lB[(wc * 64 + t * 16 + lm) * 64 + pcp];
        }
#pragma unroll
        for (int i = 0; i < 4; i++)
#pragma unroll
            for (int j = 0; j < 4; j++)
                acc[i][j] = __builtin_amdgcn_mfma_f32_16x16x32_f16(af[i], bf[j], acc[i][j], 0, 0, 0);
#pragma unroll
        for (int t = 0; t < 4; t++) {
            af[t] = *(const half8*)&lA[(wr * 64 + t * 16 + lm) * 64 + (pcp ^ 32)];
            bf[t] = *(const half8*)&lB[(wc * 64 + t * 16 + lm) * 64 + (pcp ^ 32)];
        }
#pragma unroll
        for (int i = 0; i < 4; i++)
#pragma unroll
            for (int j = 0; j < 4; j++)
                acc[i][j] = __builtin_amdgcn_mfma_f32_16x16x32_f16(af[i], bf[j], acc[i][j], 0, 0, 0);
    }
    const int col = n0 + wc * 64 + lm;
    const int rowq = q * 4;
#pragma unroll
    for (int i = 0; i < 4; i++) {
        int row = m0 + wr * 64 + i * 16 + rowq;
#pragma unroll
        for (int j = 0; j < 4; j++)
#pragma unroll
            for (int r = 0; r < 4; r++)
                C[(long)(row + r) * N + col + j * 16] = acc[i][j][r];
    }
}

// ---------------- fuse pass A: FT1[y][x] = sum_d ST[y+d][x+d] -----------------
// Coalesced 3-tap diagonal stencil (flat bounds on both axes). Per batch.
__global__ __launch_bounds__(256)
void fuseA(const float* __restrict__ ST, float* __restrict__ FT1) {
    int y = blockIdx.x;
    const float* r0 = ST + (long)(y > 0 ? y - 1 : 0) * LBF;
    const float* r1 = ST + (long)y * LBF;
    const float* r2 = ST + (long)(y < LBF - 1 ? y + 1 : y) * LBF;
    float m0 = (y > 0) ? 1.f : 0.f;
    float m2 = (y < LBF - 1) ? 1.f : 0.f;
    float* o = FT1 + (long)y * LBF;
#pragma unroll
    for (int u = 0; u < 9; u++) {
        int x = threadIdx.x + u * 256;
        float lo = (x > 0) ? m0 * r0[x - 1] : 0.f;
        float hi = (x < LBF - 1) ? m2 * r2[x + 1] : 0.f;
        o[x] = lo + r1[x] + hi;
    }
}

// ---------------- fuse pass B + masked softmax + compaction -------------------
// finalT[y][x] = sum_d2 FT1[P(P(y)+d2)][P(P(x)+d2)], P(x)=(x%48)*48+x/48.
// P(P(x)+d2) = x+48*d2 except digit carries: a+d2==48 -> b+1; a+d2==-1 -> 2255+b.
__global__ __launch_bounds__(256)
void fuseB_softmax(const float* __restrict__ FT1, const float* __restrict__ mmv,
                   const int* __restrict__ pos, _Float16* __restrict__ attTc_b) {
    int j = blockIdx.x;
    int tid = threadIdx.x;
    _Float16* orow = attTc_b + (long)j * LDK2;
    int Pj = (j % 48) * 48 + j / 48;
    long roff[3]; bool jok[3];
#pragma unroll
    for (int t = 0; t < 3; t++) {
        int j2 = Pj + t - 1;
        jok[t] = (unsigned)j2 < (unsigned)LBF;
        int jc = jok[t] ? j2 : 0;
        roff[t] = (long)((jc % 48) * 48 + jc / 48) * LBF;
    }
    float v[9], msk[9];
    float mx = -1e30f;
#pragma unroll
    for (int u = 0; u < 9; u++) {
        int x = tid + u * 256;
        float mi = mmv[x];
        msk[u] = mi;
        float xv = 0.f;
        if (mi != 0.f) {
            int a = x / 48, b = x - a * 48;
            int Px = b * 48 + a;
            float acc = 0.f;
#pragma unroll
            for (int t = 0; t < 3; t++) {
                int d2 = t - 1;
                int uu = Px + d2;
                if (jok[t] && (unsigned)uu < (unsigned)LBF) {
                    int ad = a + d2;
                    int c = ((unsigned)ad < 48u) ? (x + 48 * d2)
                          : (ad == 48 ? (b + 1) : (2255 + b));
                    acc += FT1[roff[t] + c];
                }
            }
            xv = acc * 10.f;
        }
        v[u] = xv;
        mx = fmaxf(mx, xv);
    }
    for (int m = 32; m; m >>= 1) mx = fmaxf(mx, __shfl_xor(mx, m));
    __shared__ float sh[4], sh2[4];
    if ((tid & 63) == 0) sh[tid >> 6] = mx;
    __syncthreads();
    mx = fmaxf(fmaxf(sh[0], sh[1]), fmaxf(sh[2], sh[3]));
    float sum = 0.f;
#pragma unroll
    for (int u = 0; u < 9; u++) { v[u] = __expf(v[u] - mx); sum += v[u]; }
    for (int m = 32; m; m >>= 1) sum += __shfl_xor(sum, m);
    if ((tid & 63) == 0) sh2[tid >> 6] = sum;
    __syncthreads();
    sum = sh2[0] + sh2[1] + sh2[2] + sh2[3];
    float inv = 1.f / sum;
#pragma unroll
    for (int u = 0; u < 9; u++) {
        if (msk[u] != 0.f) orow[pos[tid + u * 256]] = (_Float16)(v[u] * inv);
    }
}

// ---------------- scatter: transposed-conv gather, /4 -------------------------
__global__ void scatter_out(const float* __restrict__ Mb_, float* __restrict__ out) {
    int yx = blockIdx.x * 256 + threadIdx.x;  // [0, 9216)
    int c = blockIdx.y, b = blockIdx.z;
    int y = yx / 96, x = yx % 96;
    const float* Mb = Mb_ + (long)b * LBF * 2048;
    float s = 0.f;
    for (int uu = (y + 1) & 1; uu < 4; uu += 2) {
        int fi = (y + 1 - uu) >> 1;
        if ((unsigned)fi >= 48u) continue;
        for (int vv = (x + 1) & 1; vv < 4; vv += 2) {
            int fj = (x + 1 - vv) >> 1;
            if ((unsigned)fj >= 48u) continue;
            s += Mb[(long)(fi * 48 + fj) * 2048 + c * 16 + uu * 4 + vv];
        }
    }
    out[(((long)b * 128 + c) * 96 + y) * 96 + x] = 0.25f * s;
}

extern "C" void kernel_launch(void* const* d_in, const int* in_sizes, int n_in,
                              void* d_out, int out_size, void* d_ws, size_t ws_size,
                              hipStream_t stream) {
    const float* f    = (const float*)d_in[0];
    const float* bsrc = (const float*)d_in[1];
    const float* mask = (const float*)d_in[2];
    float* out = (float*)d_out;

    // workspace regions (reuse):
    //  R0 [0, 81MB):        ST  -> Mout
    //  R1 [81, 121.5MB):    fp+wn -> attTc
    //  R2 [121.5, 157.5MB): Wtc
    //  FT1 [157.5, 177.8MB): per-batch fuse1 buffer
    //  tail: mmv, pos, kinfo
    char* ws = (char*)d_ws;
    const size_t offR1  = 84934656;                  // ST: 4*2304*2304*4
    const size_t offWn  = offR1 + 21233664;          // fp: 4*2304*1152*2
    const size_t offWtc = offR1 + 42467328;
    const size_t offFT1 = offWtc + (size_t)4 * 2048 * LDK2 * 2;   // 165150720
    const size_t offMm  = offFT1 + (size_t)LBF * LBF * 4;         // +21233664
    const size_t offPos = offMm + 9216;
    const size_t offKin = offPos + 9216;
    const size_t NEED   = offKin + 64;
    if (ws_size < NEED) return;  // visible failure, no OOB writes

    float*    ST    = (float*)(ws + 0);
    float*    Mout  = (float*)(ws + 0);
    _Float16* fp    = (_Float16*)(ws + offR1);
    _Float16* wn    = (_Float16*)(ws + offWn);
    _Float16* attTc = (_Float16*)(ws + offR1);
    _Float16* Wtc   = (_Float16*)(ws + offWtc);
    float*    FT1   = (float*)(ws + offFT1);
    float*    mmv   = (float*)(ws + offMm);
    int*      pos   = (int*)(ws + offPos);
    int*      kinfo = (int*)(ws + offKin);

    prep_mm<<<dim3(9), 256, 0, stream>>>(mask, mmv);
    scan_mm<<<dim3(1), 256, 0, stream>>>(mmv, pos, kinfo);
    prep_fp<<<dim3(9, 2304, 4), 128, 0, stream>>>(f, fp);
    prep_wn<<<dim3(2304, 4), 128, 0, stream>>>(bsrc, wn);
    prep_wtc<<<dim3(9, 2048, 4), 256, 0, stream>>>(bsrc, mmv, pos, Wtc);
    pad_zero<<<dim3(4 * 2048), 64, 0, stream>>>(Wtc, kinfo);

    // GEMM1: ST[j,i] = sum_k fp[j,k] * wn[i,k]
    gemm_nt64<<<dim3(18, 18, 4), 256, 0, stream>>>(fp, wn, ST, 2304, 2304, K1,
        kinfo + 2, (long)2304 * K1, (long)2304 * K1, (long)2304 * 2304);

    pad_zero<<<dim3(4 * 2304), 64, 0, stream>>>(attTc, kinfo);  // after GEMM1 (region reuse)

    for (int b = 0; b < 4; b++) {
        fuseA<<<dim3(LBF), 256, 0, stream>>>(ST + (long)b * LBF * LBF, FT1);
        fuseB_softmax<<<dim3(LBF), 256, 0, stream>>>(FT1, mmv, pos,
            attTc + (long)b * LBF * LDK2);
    }

    // GEMM2 (compacted K): M[j,n] = sum_kc attTc[j,kc] * Wtc[n,kc]
    gemm_nt64<<<dim3(16, 18, 4), 256, 0, stream>>>(attTc, Wtc, Mout, 2304, 2048, LDK2,
        kinfo + 1, (long)2304 * LDK2, (long)2048 * LDK2, (long)2304 * 2048);

    scatter_out<<<dim3(36, 128, 4), 256, 0, stream>>>(Mout, out);
}

// Round 5
// 557.097 us; speedup vs baseline: 1.0536x; 1.0536x over previous
//
#include <hip/hip_runtime.h>

typedef _Float16 half8 __attribute__((ext_vector_type(8)));
typedef float floatx4 __attribute__((ext_vector_type(4)));

#define LBF 2304   // Lb == Lf
#define K1  1152
#define LDK2 2304  // worst-case compacted stride (Kc can be up to 2304)

__device__ __forceinline__ void gll16(const _Float16* g, _Float16* l) {
    __builtin_amdgcn_global_load_lds((const __attribute__((address_space(1))) void*)g,
                                     (__attribute__((address_space(3))) void*)l, 16, 0, 0);
}

// ---------------- prep: fp patches (foreground, downsampled, 3x3, pad 1) ------
__global__ void prep_fp(const float* __restrict__ f, _Float16* __restrict__ fp) {
    int k = blockIdx.x * 128 + threadIdx.x;   // [0,1152)
    int p = blockIdx.y;                       // [0,2304)
    int b = blockIdx.z;
    int c = k / 9, r = k % 9, u = r / 3, v = r % 3;
    int pi = p / 48, pj = p % 48;
    int y = pi - 1 + u, x = pj - 1 + v;
    float val = 0.f;
    if ((unsigned)y < 48u && (unsigned)x < 48u)
        val = f[(((long)b * 128 + c) * 96 + 2 * y) * 96 + 2 * x];
    fp[((long)b * LBF + p) * K1 + k] = (_Float16)val;
}

// ---------------- prep: wn normalized background patches ----------------------
__global__ void prep_wn(const float* __restrict__ bsrc, _Float16* __restrict__ wn) {
    int p = blockIdx.x, b = blockIdx.y;
    int tid = threadIdx.x;  // 128 threads, 9 elems each
    int pi = p / 48, pj = p % 48;
    float w[9];
    float ss = 0.f;
#pragma unroll
    for (int t = 0; t < 9; t++) {
        int k = tid + t * 128;
        int c = k / 9, r = k % 9, u = r / 3, v = r % 3;
        int y = pi - 1 + u, x = pj - 1 + v;
        float val = 0.f;
        if ((unsigned)y < 48u && (unsigned)x < 48u)
            val = bsrc[(((long)b * 128 + c) * 96 + 2 * y) * 96 + 2 * x];
        w[t] = val;
        ss += val * val;
    }
    for (int m = 32; m; m >>= 1) ss += __shfl_xor(ss, m);
    __shared__ float sh[2];
    if ((tid & 63) == 0) sh[tid >> 6] = ss;
    __syncthreads();
    float denom = sqrtf(sh[0] + sh[1] + 0.1152f);  // sum(w^2 + ESC)
    float inv = 1.f / denom;
#pragma unroll
    for (int t = 0; t < 9; t++) {
        int k = tid + t * 128;
        wn[((long)b * LBF + p) * K1 + k] = (_Float16)(w[t] * inv);
    }
}

// ---------------- prep: mm flags from mask ------------------------------------
__global__ void prep_mm(const float* __restrict__ mask, float* __restrict__ mm) {
    int p = blockIdx.x * 256 + threadIdx.x;
    if (p >= LBF) return;
    int pi = p / 48, pj = p % 48;
    float s = 0.f;
#pragma unroll
    for (int u = 0; u < 3; u++)
#pragma unroll
        for (int v = 0; v < 3; v++) {
            int y = pi - 1 + u, x = pj - 1 + v;
            if ((unsigned)y < 48u && (unsigned)x < 48u)
                s += mask[(8 * y) * 384 + 8 * x];
        }
    mm[p] = (s == 0.f) ? 1.f : 0.f;
}

// ---------------- scan: exclusive prefix of mm -> pos[], kinfo ----------------
__global__ void scan_mm(const float* __restrict__ mmv, int* __restrict__ pos,
                        int* __restrict__ kinfo) {
    int tid = threadIdx.x;
    int loc[9]; int s = 0;
#pragma unroll
    for (int t = 0; t < 9; t++) {
        int m = (mmv[tid * 9 + t] != 0.f);
        loc[t] = s; s += m;
    }
    __shared__ int sh[256];
    sh[tid] = s; __syncthreads();
    for (int off = 1; off < 256; off <<= 1) {
        int v = (tid >= off) ? sh[tid - off] : 0;
        __syncthreads();
        sh[tid] += v;
        __syncthreads();
    }
    int excl = sh[tid] - s;
#pragma unroll
    for (int t = 0; t < 9; t++) pos[tid * 9 + t] = excl + loc[t];
    if (tid == 255) {
        int Kc = excl + s;
        kinfo[0] = Kc;
        kinfo[1] = (Kc + 63) & ~63;
        kinfo[2] = K1;
    }
}

// ---------------- prep: compacted Wt ------------------------------------------
__global__ void prep_wtc(const float* __restrict__ bsrc, const float* __restrict__ mmv,
                         const int* __restrict__ pos, _Float16* __restrict__ wtc) {
    int p = blockIdx.x * 256 + threadIdx.x;   // [0,2304)
    int n = blockIdx.y;                       // [0,2048)
    int b = blockIdx.z;
    if (mmv[p] == 0.f) return;
    int c = n >> 4, u = (n >> 2) & 3, v = n & 3;
    int pi = p / 48, pj = p % 48;
    int y = 2 * pi - 1 + u, x = 2 * pj - 1 + v;
    float val = 0.f;
    if ((unsigned)y < 96u && (unsigned)x < 96u)
        val = bsrc[(((long)b * 128 + c) * 96 + y) * 96 + x];
    wtc[((long)b * 2048 + n) * LDK2 + pos[p]] = (_Float16)val;
}

// ---------------- zero the pad columns [Kc, Kpad) ------------------------------
__global__ void pad_zero(_Float16* __restrict__ buf, const int* __restrict__ kinfo) {
    int row = blockIdx.x;                  // flattened (batch*rows)
    int col = kinfo[0] + threadIdx.x;
    if (col < kinfo[1]) buf[(long)row * LDK2 + col] = (_Float16)0.f;
}

// ---------------- NT GEMM, BK=64, double-buffered LDS -------------------------
// One barrier per K-step: loads for tile k+1 issued before compute on tile k,
// so the vmcnt drain at the barrier overlaps ~250 cyc of MFMA+ds_read.
// Chunk XOR-swizzle (phys = logical ^ (row&7)) keeps ds_read_b128 conflict-free.
__device__ __forceinline__ void gemm_compute(const _Float16* lA, const _Float16* lB,
                                             floatx4 (&acc)[4][4],
                                             int wr, int wc, int lm, int pcp) {
    half8 af[4], bf[4];
#pragma unroll
    for (int t = 0; t < 4; t++) {
        af[t] = *(const half8*)&lA[(wr * 64 + t * 16 + lm) * 64 + pcp];
        bf[t] = *(const half8*)&lB[(wc * 64 + t * 16 + lm) * 64 + pcp];
    }
#pragma unroll
    for (int i = 0; i < 4; i++)
#pragma unroll
        for (int j = 0; j < 4; j++)
            acc[i][j] = __builtin_amdgcn_mfma_f32_16x16x32_f16(af[i], bf[j], acc[i][j], 0, 0, 0);
#pragma unroll
    for (int t = 0; t < 4; t++) {
        af[t] = *(const half8*)&lA[(wr * 64 + t * 16 + lm) * 64 + (pcp ^ 32)];
        bf[t] = *(const half8*)&lB[(wc * 64 + t * 16 + lm) * 64 + (pcp ^ 32)];
    }
#pragma unroll
    for (int i = 0; i < 4; i++)
#pragma unroll
        for (int j = 0; j < 4; j++)
            acc[i][j] = __builtin_amdgcn_mfma_f32_16x16x32_f16(af[i], bf[j], acc[i][j], 0, 0, 0);
}

__global__ __launch_bounds__(256)
void gemm_nt64(const _Float16* __restrict__ A, const _Float16* __restrict__ B,
               float* __restrict__ C, int M, int N, int ldk,
               const int* __restrict__ Kptr, long sA, long sB, long sC) {
    A += blockIdx.z * sA; B += blockIdx.z * sB; C += blockIdx.z * sC;
    const int K = Kptr[0];
    const int tid = threadIdx.x;
    const int lane = tid & 63, wave = tid >> 6;
    const int wr = wave >> 1, wc = wave & 1;
    const int m0 = blockIdx.y * 128, n0 = blockIdx.x * 128;

    __shared__ _Float16 sm[4][128 * 64];   // [buf][A=0/B=1 pairs]: 4 x 16 KB = 64 KB

    floatx4 acc[4][4] = {};

    const int lm = lane & 15, q = lane >> 4;
    const int pcp = (q ^ (lm & 7)) * 8;      // substep-0 phys offset (halves)

    // staging: wave w call c covers rows (w*4+c)*8 .. +8 (1 KB, lane-linear).
    const int srow8 = lane >> 3;
    const int gc = ((lane & 7) ^ srow8) * 8;  // global halves offset (XOR swizzle)
    const _Float16* gA[4]; const _Float16* gB[4];
    int dOff[4];
#pragma unroll
    for (int c = 0; c < 4; c++) {
        int r = (wave * 4 + c) * 8 + srow8;
        gA[c] = A + (long)(m0 + r) * ldk + gc;
        gB[c] = B + (long)(n0 + r) * ldk + gc;
        dOff[c] = (wave * 4 + c) * 512;
    }

    if (K > 0) {
        // prologue: stage tile 0 into buf 0
#pragma unroll
        for (int c = 0; c < 4; c++) gll16(gA[c], &sm[0][dOff[c]]);
#pragma unroll
        for (int c = 0; c < 4; c++) gll16(gB[c], &sm[1][dOff[c]]);
        __syncthreads();
        int k0 = 0, buf = 0;
        while (true) {
            int kn = k0 + 64;
            if (kn < K) {   // issue next tile's loads into the other buffer
                const int nb = (buf ^ 1) * 2;
#pragma unroll
                for (int c = 0; c < 4; c++) gll16(gA[c] + kn, &sm[nb][dOff[c]]);
#pragma unroll
                for (int c = 0; c < 4; c++) gll16(gB[c] + kn, &sm[nb + 1][dOff[c]]);
            }
            gemm_compute(sm[buf * 2], sm[buf * 2 + 1], acc, wr, wc, lm, pcp);
            __syncthreads();   // drains new loads + all waves done with buf
            k0 = kn; buf ^= 1;
            if (k0 >= K) break;
        }
    }

    // C/D layout: col = lane&15, row = (lane>>4)*4 + reg   [m89-verified]
    const int col = n0 + wc * 64 + lm;
    const int rowq = q * 4;
#pragma unroll
    for (int i = 0; i < 4; i++) {
        int row = m0 + wr * 64 + i * 16 + rowq;
#pragma unroll
        for (int j = 0; j < 4; j++)
#pragma unroll
            for (int r = 0; r < 4; r++)
                C[(long)(row + r) * N + col + j * 16] = acc[i][j][r];
    }
}

// ---------------- fuse pass A: FT1[y][x] = sum_d ST[y+d][x+d] -----------------
__global__ __launch_bounds__(256)
void fuseA(const float* __restrict__ ST, float* __restrict__ FT1) {
    int y = blockIdx.x;
    const float* r0 = ST + (long)(y > 0 ? y - 1 : 0) * LBF;
    const float* r1 = ST + (long)y * LBF;
    const float* r2 = ST + (long)(y < LBF - 1 ? y + 1 : y) * LBF;
    float m0 = (y > 0) ? 1.f : 0.f;
    float m2 = (y < LBF - 1) ? 1.f : 0.f;
    float* o = FT1 + (long)y * LBF;
#pragma unroll
    for (int u = 0; u < 9; u++) {
        int x = threadIdx.x + u * 256;
        float lo = (x > 0) ? m0 * r0[x - 1] : 0.f;
        float hi = (x < LBF - 1) ? m2 * r2[x + 1] : 0.f;
        o[x] = lo + r1[x] + hi;
    }
}

// ---------------- fuse pass B + masked softmax + compaction + self-pad --------
__global__ __launch_bounds__(256)
void fuseB_softmax(const float* __restrict__ FT1, const float* __restrict__ mmv,
                   const int* __restrict__ pos, const int* __restrict__ kinfo,
                   _Float16* __restrict__ attTc_b) {
    int j = blockIdx.x;
    int tid = threadIdx.x;
    _Float16* orow = attTc_b + (long)j * LDK2;
    int Pj = (j % 48) * 48 + j / 48;
    long roff[3]; bool jok[3];
#pragma unroll
    for (int t = 0; t < 3; t++) {
        int j2 = Pj + t - 1;
        jok[t] = (unsigned)j2 < (unsigned)LBF;
        int jc = jok[t] ? j2 : 0;
        roff[t] = (long)((jc % 48) * 48 + jc / 48) * LBF;
    }
    float v[9], msk[9];
    float mx = -1e30f;
#pragma unroll
    for (int u = 0; u < 9; u++) {
        int x = tid + u * 256;
        float mi = mmv[x];
        msk[u] = mi;
        float xv = 0.f;
        if (mi != 0.f) {
            int a = x / 48, b = x - a * 48;
            int Px = b * 48 + a;
            float acc = 0.f;
#pragma unroll
            for (int t = 0; t < 3; t++) {
                int d2 = t - 1;
                int uu = Px + d2;
                if (jok[t] && (unsigned)uu < (unsigned)LBF) {
                    int ad = a + d2;
                    int c = ((unsigned)ad < 48u) ? (x + 48 * d2)
                          : (ad == 48 ? (b + 1) : (2255 + b));
                    acc += FT1[roff[t] + c];
                }
            }
            xv = acc * 10.f;
        }
        v[u] = xv;
        mx = fmaxf(mx, xv);
    }
    for (int m = 32; m; m >>= 1) mx = fmaxf(mx, __shfl_xor(mx, m));
    __shared__ float sh[4], sh2[4];
    if ((tid & 63) == 0) sh[tid >> 6] = mx;
    __syncthreads();
    mx = fmaxf(fmaxf(sh[0], sh[1]), fmaxf(sh[2], sh[3]));
    float sum = 0.f;
#pragma unroll
    for (int u = 0; u < 9; u++) { v[u] = __expf(v[u] - mx); sum += v[u]; }
    for (int m = 32; m; m >>= 1) sum += __shfl_xor(sum, m);
    if ((tid & 63) == 0) sh2[tid >> 6] = sum;
    __syncthreads();
    sum = sh2[0] + sh2[1] + sh2[2] + sh2[3];
    float inv = 1.f / sum;
#pragma unroll
    for (int u = 0; u < 9; u++) {
        if (msk[u] != 0.f) orow[pos[tid + u * 256]] = (_Float16)(v[u] * inv);
    }
    // self-pad: zero columns [Kc, Kpad) of this row (replaces pad_zero launch)
    int kc = kinfo[0], kp = kinfo[1];
    if (tid < kp - kc) orow[kc + tid] = (_Float16)0.f;
}

// ---------------- scatter: transposed-conv gather, /4 -------------------------
__global__ void scatter_out(const float* __restrict__ Mb_, float* __restrict__ out) {
    int yx = blockIdx.x * 256 + threadIdx.x;  // [0, 9216)
    int c = blockIdx.y, b = blockIdx.z;
    int y = yx / 96, x = yx % 96;
    const float* Mb = Mb_ + (long)b * LBF * 2048;
    float s = 0.f;
    for (int uu = (y + 1) & 1; uu < 4; uu += 2) {
        int fi = (y + 1 - uu) >> 1;
        if ((unsigned)fi >= 48u) continue;
        for (int vv = (x + 1) & 1; vv < 4; vv += 2) {
            int fj = (x + 1 - vv) >> 1;
            if ((unsigned)fj >= 48u) continue;
            s += Mb[(long)(fi * 48 + fj) * 2048 + c * 16 + uu * 4 + vv];
        }
    }
    out[(((long)b * 128 + c) * 96 + y) * 96 + x] = 0.25f * s;
}

extern "C" void kernel_launch(void* const* d_in, const int* in_sizes, int n_in,
                              void* d_out, int out_size, void* d_ws, size_t ws_size,
                              hipStream_t stream) {
    const float* f    = (const float*)d_in[0];
    const float* bsrc = (const float*)d_in[1];
    const float* mask = (const float*)d_in[2];
    float* out = (float*)d_out;

    char* ws = (char*)d_ws;
    const size_t offR1  = 84934656;                  // ST: 4*2304*2304*4
    const size_t offWn  = offR1 + 21233664;          // fp: 4*2304*1152*2
    const size_t offWtc = offR1 + 42467328;
    const size_t offFT1 = offWtc + (size_t)4 * 2048 * LDK2 * 2;   // 165150720
    const size_t offMm  = offFT1 + (size_t)LBF * LBF * 4;         // +21233664
    const size_t offPos = offMm + 9216;
    const size_t offKin = offPos + 9216;
    const size_t NEED   = offKin + 64;
    if (ws_size < NEED) return;  // visible failure, no OOB writes

    float*    ST    = (float*)(ws + 0);
    float*    Mout  = (float*)(ws + 0);
    _Float16* fp    = (_Float16*)(ws + offR1);
    _Float16* wn    = (_Float16*)(ws + offWn);
    _Float16* attTc = (_Float16*)(ws + offR1);
    _Float16* Wtc   = (_Float16*)(ws + offWtc);
    float*    FT1   = (float*)(ws + offFT1);
    float*    mmv   = (float*)(ws + offMm);
    int*      pos   = (int*)(ws + offPos);
    int*      kinfo = (int*)(ws + offKin);

    prep_mm<<<dim3(9), 256, 0, stream>>>(mask, mmv);
    scan_mm<<<dim3(1), 256, 0, stream>>>(mmv, pos, kinfo);
    prep_fp<<<dim3(9, 2304, 4), 128, 0, stream>>>(f, fp);
    prep_wn<<<dim3(2304, 4), 128, 0, stream>>>(bsrc, wn);
    prep_wtc<<<dim3(9, 2048, 4), 256, 0, stream>>>(bsrc, mmv, pos, Wtc);
    pad_zero<<<dim3(4 * 2048), 64, 0, stream>>>(Wtc, kinfo);

    // GEMM1: ST[j,i] = sum_k fp[j,k] * wn[i,k]
    gemm_nt64<<<dim3(18, 18, 4), 256, 0, stream>>>(fp, wn, ST, 2304, 2304, K1,
        kinfo + 2, (long)2304 * K1, (long)2304 * K1, (long)2304 * 2304);

    for (int b = 0; b < 4; b++) {
        fuseA<<<dim3(LBF), 256, 0, stream>>>(ST + (long)b * LBF * LBF, FT1);
        fuseB_softmax<<<dim3(LBF), 256, 0, stream>>>(FT1, mmv, pos, kinfo,
            attTc + (long)b * LBF * LDK2);
    }

    // GEMM2 (compacted K): M[j,n] = sum_kc attTc[j,kc] * Wtc[n,kc]
    gemm_nt64<<<dim3(16, 18, 4), 256, 0, stream>>>(attTc, Wtc, Mout, 2304, 2048, LDK2,
        kinfo + 1, (long)2304 * LDK2, (long)2048 * LDK2, (long)2304 * 2048);

    scatter_out<<<dim3(36, 128, 4), 256, 0, stream>>>(Mout, out);
}

// Round 6
// 497.614 us; speedup vs baseline: 1.1795x; 1.1195x over previous
//
#include <hip/hip_runtime.h>

typedef _Float16 half8 __attribute__((ext_vector_type(8)));
typedef float floatx4 __attribute__((ext_vector_type(4)));

#define LBF 2304   // Lb == Lf
#define K1  1152
#define LDK2 2304  // worst-case compacted stride (Kc can be up to 2304)

__device__ __forceinline__ void gll16(const _Float16* g, _Float16* l) {
    __builtin_amdgcn_global_load_lds((const __attribute__((address_space(1))) void*)g,
                                     (__attribute__((address_space(3))) void*)l, 16, 0, 0);
}

// decode Kc from signed pos'[2303] (excl-scan encoding: valid->e, masked->-e-1)
__device__ __forceinline__ int dec_kc(int s) { return (s >= 0) ? s + 1 : -s - 1; }

// ---------------- prep: fp patches (foreground, downsampled, 3x3, pad 1) ------
__global__ void prep_fp(const float* __restrict__ f, _Float16* __restrict__ fp) {
    int k = blockIdx.x * 128 + threadIdx.x;   // [0,1152)
    int p = blockIdx.y;                       // [0,2304)
    int b = blockIdx.z;
    int c = k / 9, r = k % 9, u = r / 3, v = r % 3;
    int pi = p / 48, pj = p % 48;
    int y = pi - 1 + u, x = pj - 1 + v;
    float val = 0.f;
    if ((unsigned)y < 48u && (unsigned)x < 48u)
        val = f[(((long)b * 128 + c) * 96 + 2 * y) * 96 + 2 * x];
    fp[((long)b * LBF + p) * K1 + k] = (_Float16)val;
}

// ---------------- prep: wn normalized background patches ----------------------
__global__ void prep_wn(const float* __restrict__ bsrc, _Float16* __restrict__ wn) {
    int p = blockIdx.x, b = blockIdx.y;
    int tid = threadIdx.x;  // 128 threads, 9 elems each
    int pi = p / 48, pj = p % 48;
    float w[9];
    float ss = 0.f;
#pragma unroll
    for (int t = 0; t < 9; t++) {
        int k = tid + t * 128;
        int c = k / 9, r = k % 9, u = r / 3, v = r % 3;
        int y = pi - 1 + u, x = pj - 1 + v;
        float val = 0.f;
        if ((unsigned)y < 48u && (unsigned)x < 48u)
            val = bsrc[(((long)b * 128 + c) * 96 + 2 * y) * 96 + 2 * x];
        w[t] = val;
        ss += val * val;
    }
    for (int m = 32; m; m >>= 1) ss += __shfl_xor(ss, m);
    __shared__ float sh[2];
    if ((tid & 63) == 0) sh[tid >> 6] = ss;
    __syncthreads();
    float denom = sqrtf(sh[0] + sh[1] + 0.1152f);  // sum(w^2 + ESC)
    float inv = 1.f / denom;
#pragma unroll
    for (int t = 0; t < 9; t++) {
        int k = tid + t * 128;
        wn[((long)b * LBF + p) * K1 + k] = (_Float16)(w[t] * inv);
    }
}

// ---------------- mask -> signed compaction index pos' (merged prep_mm+scan) --
// pos'[p] = excl_scan_of_valid  if p valid (mm==1), else -excl-1.
__global__ void scan_mm(const float* __restrict__ mask, int* __restrict__ pos) {
    int tid = threadIdx.x;  // 256 threads x 9 p's
    int mmb[9], loc[9]; int s = 0;
#pragma unroll
    for (int t = 0; t < 9; t++) {
        int p = tid * 9 + t;
        int pi = p / 48, pj = p % 48;
        float sm = 0.f;
#pragma unroll
        for (int u = 0; u < 3; u++)
#pragma unroll
            for (int v = 0; v < 3; v++) {
                int y = pi - 1 + u, x = pj - 1 + v;
                if ((unsigned)y < 48u && (unsigned)x < 48u)
                    sm += mask[(8 * y) * 384 + 8 * x];
            }
        int m = (sm == 0.f) ? 1 : 0;
        mmb[t] = m; loc[t] = s; s += m;
    }
    __shared__ int sh[256];
    sh[tid] = s; __syncthreads();
    for (int off = 1; off < 256; off <<= 1) {
        int v = (tid >= off) ? sh[tid - off] : 0;
        __syncthreads();
        sh[tid] += v;
        __syncthreads();
    }
    int excl = sh[tid] - s;
#pragma unroll
    for (int t = 0; t < 9; t++) {
        int e = excl + loc[t];
        pos[tid * 9 + t] = mmb[t] ? e : (-e - 1);
    }
}

// ---------------- prep: compacted Wt ------------------------------------------
__global__ void prep_wtc(const float* __restrict__ bsrc, const int* __restrict__ pos,
                         _Float16* __restrict__ wtc) {
    int p = blockIdx.x * 256 + threadIdx.x;   // [0,2304)
    int n = blockIdx.y;                       // [0,2048)
    int b = blockIdx.z;
    int sp = pos[p];
    if (sp < 0) return;
    int c = n >> 4, u = (n >> 2) & 3, v = n & 3;
    int pi = p / 48, pj = p % 48;
    int y = 2 * pi - 1 + u, x = 2 * pj - 1 + v;
    float val = 0.f;
    if ((unsigned)y < 96u && (unsigned)x < 96u)
        val = bsrc[(((long)b * 128 + c) * 96 + y) * 96 + x];
    wtc[((long)b * 2048 + n) * LDK2 + sp] = (_Float16)val;
}

// ---------------- zero the pad columns [Kc, Kpad) of Wtc ----------------------
__global__ void pad_zero(_Float16* __restrict__ buf, const int* __restrict__ pos) {
    int row = blockIdx.x;                  // flattened (batch*rows)
    int kc = dec_kc(pos[2303]);
    int kp = (kc + 63) & ~63;
    int col = kc + threadIdx.x;
    if (col < kp) buf[(long)row * LDK2 + col] = (_Float16)0.f;
}

// ---------------- NT GEMM, BK=64, double-buffered LDS -------------------------
// One barrier per K-step: loads for tile k+1 issued before compute on tile k.
// Chunk XOR-swizzle (phys = logical ^ (row&7)) keeps ds_read_b128 conflict-free.
__device__ __forceinline__ void gemm_compute(const _Float16* lA, const _Float16* lB,
                                             floatx4 (&acc)[4][4],
                                             int wr, int wc, int lm, int pcp) {
    half8 af[4], bf[4];
#pragma unroll
    for (int t = 0; t < 4; t++) {
        af[t] = *(const half8*)&lA[(wr * 64 + t * 16 + lm) * 64 + pcp];
        bf[t] = *(const half8*)&lB[(wc * 64 + t * 16 + lm) * 64 + pcp];
    }
#pragma unroll
    for (int i = 0; i < 4; i++)
#pragma unroll
        for (int j = 0; j < 4; j++)
            acc[i][j] = __builtin_amdgcn_mfma_f32_16x16x32_f16(af[i], bf[j], acc[i][j], 0, 0, 0);
#pragma unroll
    for (int t = 0; t < 4; t++) {
        af[t] = *(const half8*)&lA[(wr * 64 + t * 16 + lm) * 64 + (pcp ^ 32)];
        bf[t] = *(const half8*)&lB[(wc * 64 + t * 16 + lm) * 64 + (pcp ^ 32)];
    }
#pragma unroll
    for (int i = 0; i < 4; i++)
#pragma unroll
        for (int j = 0; j < 4; j++)
            acc[i][j] = __builtin_amdgcn_mfma_f32_16x16x32_f16(af[i], bf[j], acc[i][j], 0, 0, 0);
}

__global__ __launch_bounds__(256)
void gemm_nt64(const _Float16* __restrict__ A, const _Float16* __restrict__ B,
               float* __restrict__ C, int M, int N, int ldk,
               const int* __restrict__ Kpos, int Kstat, long sA, long sB, long sC) {
    A += blockIdx.z * sA; B += blockIdx.z * sB; C += blockIdx.z * sC;
    int K;
    if (Kpos) { int kc = dec_kc(Kpos[0]); K = (kc + 63) & ~63; }
    else K = Kstat;
    const int tid = threadIdx.x;
    const int lane = tid & 63, wave = tid >> 6;
    const int wr = wave >> 1, wc = wave & 1;
    const int m0 = blockIdx.y * 128, n0 = blockIdx.x * 128;

    __shared__ _Float16 sm[4][128 * 64];   // [buf*2 + (A=0/B=1)]: 4 x 16 KB

    floatx4 acc[4][4] = {};

    const int lm = lane & 15, q = lane >> 4;
    const int pcp = (q ^ (lm & 7)) * 8;      // substep-0 phys offset (halves)

    const int srow8 = lane >> 3;
    const int gc = ((lane & 7) ^ srow8) * 8;  // global halves offset (XOR swizzle)
    const _Float16* gA[4]; const _Float16* gB[4];
    int dOff[4];
#pragma unroll
    for (int c = 0; c < 4; c++) {
        int r = (wave * 4 + c) * 8 + srow8;
        gA[c] = A + (long)(m0 + r) * ldk + gc;
        gB[c] = B + (long)(n0 + r) * ldk + gc;
        dOff[c] = (wave * 4 + c) * 512;
    }

    if (K > 0) {
#pragma unroll
        for (int c = 0; c < 4; c++) gll16(gA[c], &sm[0][dOff[c]]);
#pragma unroll
        for (int c = 0; c < 4; c++) gll16(gB[c], &sm[1][dOff[c]]);
        __syncthreads();
        int k0 = 0, buf = 0;
        while (true) {
            int kn = k0 + 64;
            if (kn < K) {
                const int nb = (buf ^ 1) * 2;
#pragma unroll
                for (int c = 0; c < 4; c++) gll16(gA[c] + kn, &sm[nb][dOff[c]]);
#pragma unroll
                for (int c = 0; c < 4; c++) gll16(gB[c] + kn, &sm[nb + 1][dOff[c]]);
            }
            gemm_compute(sm[buf * 2], sm[buf * 2 + 1], acc, wr, wc, lm, pcp);
            __syncthreads();
            k0 = kn; buf ^= 1;
            if (k0 >= K) break;
        }
    }

    // C/D layout: col = lane&15, row = (lane>>4)*4 + reg   [m89-verified]
    const int col = n0 + wc * 64 + lm;
    const int rowq = q * 4;
#pragma unroll
    for (int i = 0; i < 4; i++) {
        int row = m0 + wr * 64 + i * 16 + rowq;
#pragma unroll
        for (int j = 0; j < 4; j++)
#pragma unroll
            for (int r = 0; r < 4; r++)
                C[(long)(row + r) * N + col + j * 16] = acc[i][j][r];
    }
}

// ---------------- fuse pass A: FT1[y][x] = sum_d ST[y+d][x+d] -----------------
// grid (2304, 2): y = blockIdx.x, sub-batch = blockIdx.y
__global__ __launch_bounds__(256)
void fuseA(const float* __restrict__ ST, float* __restrict__ FT1) {
    int y = blockIdx.x, bb = blockIdx.y;
    const float* S = ST + (long)bb * LBF * LBF;
    float* F = FT1 + (long)bb * LBF * LBF;
    const float* r0 = S + (long)(y > 0 ? y - 1 : 0) * LBF;
    const float* r1 = S + (long)y * LBF;
    const float* r2 = S + (long)(y < LBF - 1 ? y + 1 : y) * LBF;
    float m0 = (y > 0) ? 1.f : 0.f;
    float m2 = (y < LBF - 1) ? 1.f : 0.f;
    float* o = F + (long)y * LBF;
#pragma unroll
    for (int u = 0; u < 9; u++) {
        int x = threadIdx.x + u * 256;
        float lo = (x > 0) ? m0 * r0[x - 1] : 0.f;
        float hi = (x < LBF - 1) ? m2 * r2[x + 1] : 0.f;
        o[x] = lo + r1[x] + hi;
    }
}

// ---------------- fuse pass B + masked softmax + compaction + self-pad --------
__global__ __launch_bounds__(256)
void fuseB_softmax(const float* __restrict__ FT1, const int* __restrict__ pos,
                   _Float16* __restrict__ attTc_g) {
    int j = blockIdx.x, bb = blockIdx.y;
    int tid = threadIdx.x;
    const float* F = FT1 + (long)bb * LBF * LBF;
    _Float16* orow = attTc_g + ((long)bb * LBF + j) * LDK2;
    int Pj = (j % 48) * 48 + j / 48;
    long roff[3]; bool jok[3];
#pragma unroll
    for (int t = 0; t < 3; t++) {
        int j2 = Pj + t - 1;
        jok[t] = (unsigned)j2 < (unsigned)LBF;
        int jc = jok[t] ? j2 : 0;
        roff[t] = (long)((jc % 48) * 48 + jc / 48) * LBF;
    }
    float v[9]; int ps[9];
    float mx = -1e30f;
#pragma unroll
    for (int u = 0; u < 9; u++) {
        int x = tid + u * 256;
        int sp = pos[x];
        ps[u] = sp;
        float xv = 0.f;
        if (sp >= 0) {
            int a = x / 48, b = x - a * 48;
            int Px = b * 48 + a;
            float acc = 0.f;
#pragma unroll
            for (int t = 0; t < 3; t++) {
                int d2 = t - 1;
                int uu = Px + d2;
                if (jok[t] && (unsigned)uu < (unsigned)LBF) {
                    int ad = a + d2;
                    int c = ((unsigned)ad < 48u) ? (x + 48 * d2)
                          : (ad == 48 ? (b + 1) : (2255 + b));
                    acc += F[roff[t] + c];
                }
            }
            xv = acc * 10.f;
        }
        v[u] = xv;
        mx = fmaxf(mx, xv);
    }
    for (int m = 32; m; m >>= 1) mx = fmaxf(mx, __shfl_xor(mx, m));
    __shared__ float sh[4], sh2[4];
    if ((tid & 63) == 0) sh[tid >> 6] = mx;
    __syncthreads();
    mx = fmaxf(fmaxf(sh[0], sh[1]), fmaxf(sh[2], sh[3]));
    float sum = 0.f;
#pragma unroll
    for (int u = 0; u < 9; u++) { v[u] = __expf(v[u] - mx); sum += v[u]; }
    for (int m = 32; m; m >>= 1) sum += __shfl_xor(sum, m);
    if ((tid & 63) == 0) sh2[tid >> 6] = sum;
    __syncthreads();
    sum = sh2[0] + sh2[1] + sh2[2] + sh2[3];
    float inv = 1.f / sum;
#pragma unroll
    for (int u = 0; u < 9; u++) {
        if (ps[u] >= 0) orow[ps[u]] = (_Float16)(v[u] * inv);
    }
    // self-pad: zero columns [Kc, Kpad)
    int kc = dec_kc(pos[2303]);
    int kp = (kc + 63) & ~63;
    if (tid < kp - kc) orow[kc + tid] = (_Float16)0.f;
}

// ---------------- scatter from MT[n][p]: coalesced transposed-conv gather -----
__global__ void scatter_out(const float* __restrict__ MT_, float* __restrict__ out) {
    int yx = blockIdx.x * 256 + threadIdx.x;  // [0, 9216)
    int c = blockIdx.y, b = blockIdx.z;
    int y = yx / 96, x = yx % 96;
    const float* Mb = MT_ + (long)b * 2048 * LBF;
    float s = 0.f;
    for (int uu = (y + 1) & 1; uu < 4; uu += 2) {
        int fi = (y + 1 - uu) >> 1;
        if ((unsigned)fi >= 48u) continue;
        for (int vv = (x + 1) & 1; vv < 4; vv += 2) {
            int fj = (x + 1 - vv) >> 1;
            if ((unsigned)fj >= 48u) continue;
            s += Mb[(long)(c * 16 + uu * 4 + vv) * LBF + fi * 48 + fj];
        }
    }
    out[(((long)b * 128 + c) * 96 + y) * 96 + x] = 0.25f * s;
}

extern "C" void kernel_launch(void* const* d_in, const int* in_sizes, int n_in,
                              void* d_out, int out_size, void* d_ws, size_t ws_size,
                              hipStream_t stream) {
    const float* f    = (const float*)d_in[0];
    const float* bsrc = (const float*)d_in[1];
    const float* mask = (const float*)d_in[2];
    float* out = (float*)d_out;

    // workspace regions (reuse; NEED == 207627264 == proven-available from R2):
    //  ST   [0, 85MB)          -> MT (75.5MB) after fuse
    //  fp/wn [85, 127.4MB)     -> attTc
    //  Wtc  [127.4, 165.2MB)
    //  FT1x2 [165.2, 207.62MB)
    //  pos' [207.618048, +9216)
    char* ws = (char*)d_ws;
    const size_t offR1  = 84934656;
    const size_t offWn  = offR1 + 21233664;
    const size_t offWtc = offR1 + 42467328;
    const size_t offFT1 = offWtc + 37748736;          // 165150720
    const size_t offPos = offFT1 + 2ul * 21233664;    // 207618048
    const size_t NEED   = offPos + 9216;              // 207627264
    if (ws_size < NEED) return;  // visible failure, no OOB writes

    float*    ST    = (float*)(ws + 0);
    float*    MT    = (float*)(ws + 0);
    _Float16* fp    = (_Float16*)(ws + offR1);
    _Float16* wn    = (_Float16*)(ws + offWn);
    _Float16* attTc = (_Float16*)(ws + offR1);
    _Float16* Wtc   = (_Float16*)(ws + offWtc);
    float*    FT1   = (float*)(ws + offFT1);
    int*      pos   = (int*)(ws + offPos);

    scan_mm<<<dim3(1), 256, 0, stream>>>(mask, pos);
    prep_fp<<<dim3(9, 2304, 4), 128, 0, stream>>>(f, fp);
    prep_wn<<<dim3(2304, 4), 128, 0, stream>>>(bsrc, wn);
    prep_wtc<<<dim3(9, 2048, 4), 256, 0, stream>>>(bsrc, pos, Wtc);
    pad_zero<<<dim3(4 * 2048), 64, 0, stream>>>(Wtc, pos);

    // GEMM1: ST[j,i] = sum_k fp[j,k] * wn[i,k]  (static K=1152)
    gemm_nt64<<<dim3(18, 18, 4), 256, 0, stream>>>(fp, wn, ST, 2304, 2304, K1,
        nullptr, K1, (long)2304 * K1, (long)2304 * K1, (long)2304 * 2304);

    for (int g = 0; g < 2; g++) {
        fuseA<<<dim3(LBF, 2), 256, 0, stream>>>(ST + (long)g * 2 * LBF * LBF, FT1);
        fuseB_softmax<<<dim3(LBF, 2), 256, 0, stream>>>(FT1, pos,
            attTc + (long)g * 2 * LBF * LDK2);
    }

    // GEMM2 transposed: MT[n,p] = sum_kc Wtc[n,kc] * attTc[p,kc]  (dynamic Kpad)
    gemm_nt64<<<dim3(18, 16, 4), 256, 0, stream>>>(Wtc, attTc, MT, 2048, 2304, LDK2,
        pos + 2303, 0, (long)2048 * LDK2, (long)2304 * LDK2, (long)2048 * 2304);

    scatter_out<<<dim3(36, 128, 4), 256, 0, stream>>>(MT, out);
}

// Round 7
// 474.216 us; speedup vs baseline: 1.2377x; 1.0493x over previous
//
#include <hip/hip_runtime.h>

typedef _Float16 half8 __attribute__((ext_vector_type(8)));
typedef float floatx4 __attribute__((ext_vector_type(4)));

#define LBF 2304   // Lb == Lf
#define K1  1152
#define LDK2 2304  // worst-case compacted stride (Kc can be up to 2304)

__device__ __forceinline__ void gll16(const _Float16* g, _Float16* l) {
    __builtin_amdgcn_global_load_lds((const __attribute__((address_space(1))) void*)g,
                                     (__attribute__((address_space(3))) void*)l, 16, 0, 0);
}

// decode Kc from signed pos'[2303] (excl-scan encoding: valid->e, masked->-e-1)
__device__ __forceinline__ int dec_kc(int s) { return (s >= 0) ? s + 1 : -s - 1; }

// ---------------- stage: downsampled f,b planes -> compact ds ------------------
// ds[((t*4+b)*128+c)*2304 + pi*48+pj] = src[..., 2*pi, 2*pj]
__global__ void stage_ds(const float* __restrict__ f, const float* __restrict__ bsrc,
                         float* __restrict__ ds) {
    long flat = (long)blockIdx.x * 256 + threadIdx.x;   // [0, 2*4*128*2304)
    int p = flat % 2304;
    long rest = flat / 2304;
    int c = rest % 128;
    int b = (rest / 128) % 4;
    int t = rest / (128 * 4);
    int pi = p / 48, pj = p % 48;
    const float* src = t ? bsrc : f;
    ds[flat] = src[(((long)b * 128 + c) * 96 + 2 * pi) * 96 + 2 * pj];
}

// ---------------- prep: fp patches from ds (3x3, pad 1) ------------------------
__global__ void prep_fp(const float* __restrict__ ds, _Float16* __restrict__ fp) {
    int k = blockIdx.x * 128 + threadIdx.x;   // [0,1152)
    int p = blockIdx.y;                       // [0,2304)
    int b = blockIdx.z;
    int c = k / 9, r = k % 9, u = r / 3, v = r % 3;
    int pi = p / 48, pj = p % 48;
    int y = pi - 1 + u, x = pj - 1 + v;
    float val = 0.f;
    if ((unsigned)y < 48u && (unsigned)x < 48u)
        val = ds[((long)(b * 128 + c)) * 2304 + y * 48 + x];
    fp[((long)b * LBF + p) * K1 + k] = (_Float16)val;
}

// ---------------- prep: wn normalized background patches from ds ---------------
__global__ void prep_wn(const float* __restrict__ ds, _Float16* __restrict__ wn) {
    int p = blockIdx.x, b = blockIdx.y;
    int tid = threadIdx.x;  // 128 threads, 9 elems each
    int pi = p / 48, pj = p % 48;
    const float* dsb = ds + (long)(4 + b) * 128 * 2304;
    float w[9];
    float ss = 0.f;
#pragma unroll
    for (int t = 0; t < 9; t++) {
        int k = tid + t * 128;
        int c = k / 9, r = k % 9, u = r / 3, v = r % 3;
        int y = pi - 1 + u, x = pj - 1 + v;
        float val = 0.f;
        if ((unsigned)y < 48u && (unsigned)x < 48u)
            val = dsb[(long)c * 2304 + y * 48 + x];
        w[t] = val;
        ss += val * val;
    }
    for (int m = 32; m; m >>= 1) ss += __shfl_xor(ss, m);
    __shared__ float sh[2];
    if ((tid & 63) == 0) sh[tid >> 6] = ss;
    __syncthreads();
    float denom = sqrtf(sh[0] + sh[1] + 0.1152f);  // sum(w^2 + ESC)
    float inv = 1.f / denom;
#pragma unroll
    for (int t = 0; t < 9; t++) {
        int k = tid + t * 128;
        wn[((long)b * LBF + p) * K1 + k] = (_Float16)(w[t] * inv);
    }
}

// ---------------- mask -> signed compaction index pos' -------------------------
__global__ void scan_mm(const float* __restrict__ mask, int* __restrict__ pos) {
    int tid = threadIdx.x;  // 256 threads x 9 p's
    int mmb[9], loc[9]; int s = 0;
#pragma unroll
    for (int t = 0; t < 9; t++) {
        int p = tid * 9 + t;
        int pi = p / 48, pj = p % 48;
        float sm = 0.f;
#pragma unroll
        for (int u = 0; u < 3; u++)
#pragma unroll
            for (int v = 0; v < 3; v++) {
                int y = pi - 1 + u, x = pj - 1 + v;
                if ((unsigned)y < 48u && (unsigned)x < 48u)
                    sm += mask[(8 * y) * 384 + 8 * x];
            }
        int m = (sm == 0.f) ? 1 : 0;
        mmb[t] = m; loc[t] = s; s += m;
    }
    __shared__ int sh[256];
    sh[tid] = s; __syncthreads();
    for (int off = 1; off < 256; off <<= 1) {
        int v = (tid >= off) ? sh[tid - off] : 0;
        __syncthreads();
        sh[tid] += v;
        __syncthreads();
    }
    int excl = sh[tid] - s;
#pragma unroll
    for (int t = 0; t < 9; t++) {
        int e = excl + loc[t];
        pos[tid * 9 + t] = mmb[t] ? e : (-e - 1);
    }
}

// ---------------- prep: compacted Wt + self-pad of [Kc, Kpad) ------------------
__global__ void prep_wtc(const float* __restrict__ bsrc, const int* __restrict__ pos,
                         _Float16* __restrict__ wtc) {
    int p = blockIdx.x * 256 + threadIdx.x;   // [0,2304)
    int n = blockIdx.y;                       // [0,2048)
    int b = blockIdx.z;
    int sp = pos[p];
    if (sp < 0) {
        // masked ordinal covers pad columns exactly once
        int kc = dec_kc(pos[2303]);
        int kp = (kc + 63) & ~63;
        int mo = p + sp + 1;                  // p - (#valid before p)
        if (mo < kp - kc)
            wtc[((long)b * 2048 + n) * LDK2 + kc + mo] = (_Float16)0.f;
        return;
    }
    int c = n >> 4, u = (n >> 2) & 3, v = n & 3;
    int pi = p / 48, pj = p % 48;
    int y = 2 * pi - 1 + u, x = 2 * pj - 1 + v;
    float val = 0.f;
    if ((unsigned)y < 96u && (unsigned)x < 96u)
        val = bsrc[(((long)b * 128 + c) * 96 + y) * 96 + x];
    wtc[((long)b * 2048 + n) * LDK2 + sp] = (_Float16)val;
}

// ---------------- NT GEMM, BK=64, double-buffered LDS -------------------------
__device__ __forceinline__ void gemm_compute(const _Float16* lA, const _Float16* lB,
                                             floatx4 (&acc)[4][4],
                                             int wr, int wc, int lm, int pcp) {
    half8 af[4], bf[4];
#pragma unroll
    for (int t = 0; t < 4; t++) {
        af[t] = *(const half8*)&lA[(wr * 64 + t * 16 + lm) * 64 + pcp];
        bf[t] = *(const half8*)&lB[(wc * 64 + t * 16 + lm) * 64 + pcp];
    }
#pragma unroll
    for (int i = 0; i < 4; i++)
#pragma unroll
        for (int j = 0; j < 4; j++)
            acc[i][j] = __builtin_amdgcn_mfma_f32_16x16x32_f16(af[i], bf[j], acc[i][j], 0, 0, 0);
#pragma unroll
    for (int t = 0; t < 4; t++) {
        af[t] = *(const half8*)&lA[(wr * 64 + t * 16 + lm) * 64 + (pcp ^ 32)];
        bf[t] = *(const half8*)&lB[(wc * 64 + t * 16 + lm) * 64 + (pcp ^ 32)];
    }
#pragma unroll
    for (int i = 0; i < 4; i++)
#pragma unroll
        for (int j = 0; j < 4; j++)
            acc[i][j] = __builtin_amdgcn_mfma_f32_16x16x32_f16(af[i], bf[j], acc[i][j], 0, 0, 0);
}

__global__ __launch_bounds__(256)
void gemm_nt64(const _Float16* __restrict__ A, const _Float16* __restrict__ B,
               float* __restrict__ C, int M, int N, int ldk, int swapxy,
               const int* __restrict__ Kpos, int Kstat, long sA, long sB, long sC) {
    A += blockIdx.z * sA; B += blockIdx.z * sB; C += blockIdx.z * sC;
    int K;
    if (Kpos) { int kc = dec_kc(Kpos[0]); K = (kc + 63) & ~63; }
    else K = Kstat;
    const int tid = threadIdx.x;
    const int lane = tid & 63, wave = tid >> 6;
    const int wr = wave >> 1, wc = wave & 1;
    const int bm = swapxy ? blockIdx.x : blockIdx.y;
    const int bn = swapxy ? blockIdx.y : blockIdx.x;
    const int m0 = bm * 128, n0 = bn * 128;

    __shared__ _Float16 sm[4][128 * 64];   // [buf*2 + (A=0/B=1)]: 4 x 16 KB

    floatx4 acc[4][4] = {};

    const int lm = lane & 15, q = lane >> 4;
    const int pcp = (q ^ (lm & 7)) * 8;      // substep-0 phys offset (halves)

    const int srow8 = lane >> 3;
    const int gc = ((lane & 7) ^ srow8) * 8;  // global halves offset (XOR swizzle)
    const _Float16* gA[4]; const _Float16* gB[4];
    int dOff[4];
#pragma unroll
    for (int c = 0; c < 4; c++) {
        int r = (wave * 4 + c) * 8 + srow8;
        gA[c] = A + (long)(m0 + r) * ldk + gc;
        gB[c] = B + (long)(n0 + r) * ldk + gc;
        dOff[c] = (wave * 4 + c) * 512;
    }

    if (K > 0) {
#pragma unroll
        for (int c = 0; c < 4; c++) gll16(gA[c], &sm[0][dOff[c]]);
#pragma unroll
        for (int c = 0; c < 4; c++) gll16(gB[c], &sm[1][dOff[c]]);
        __syncthreads();
        int k0 = 0, buf = 0;
        while (true) {
            int kn = k0 + 64;
            if (kn < K) {
                const int nb = (buf ^ 1) * 2;
#pragma unroll
                for (int c = 0; c < 4; c++) gll16(gA[c] + kn, &sm[nb][dOff[c]]);
#pragma unroll
                for (int c = 0; c < 4; c++) gll16(gB[c] + kn, &sm[nb + 1][dOff[c]]);
            }
            gemm_compute(sm[buf * 2], sm[buf * 2 + 1], acc, wr, wc, lm, pcp);
            __syncthreads();
            k0 = kn; buf ^= 1;
            if (k0 >= K) break;
        }
    }

    // C/D layout: col = lane&15, row = (lane>>4)*4 + reg   [m89-verified]
    const int col = n0 + wc * 64 + lm;
    const int rowq = q * 4;
#pragma unroll
    for (int i = 0; i < 4; i++) {
        int row = m0 + wr * 64 + i * 16 + rowq;
#pragma unroll
        for (int j = 0; j < 4; j++)
#pragma unroll
            for (int r = 0; r < 4; r++)
                C[(long)(row + r) * N + col + j * 16] = acc[i][j][r];
    }
}

// ---------------- fuse pass A: FT1[y][x] = sum_d ST[y+d][x+d] -----------------
__global__ __launch_bounds__(256)
void fuseA(const float* __restrict__ ST, float* __restrict__ FT1) {
    int y = blockIdx.x, bb = blockIdx.y;
    const float* S = ST + (long)bb * LBF * LBF;
    float* F = FT1 + (long)bb * LBF * LBF;
    const float* r0 = S + (long)(y > 0 ? y - 1 : 0) * LBF;
    const float* r1 = S + (long)y * LBF;
    const float* r2 = S + (long)(y < LBF - 1 ? y + 1 : y) * LBF;
    float m0 = (y > 0) ? 1.f : 0.f;
    float m2 = (y < LBF - 1) ? 1.f : 0.f;
    float* o = F + (long)y * LBF;
#pragma unroll
    for (int u = 0; u < 9; u++) {
        int x = threadIdx.x + u * 256;
        float lo = (x > 0) ? m0 * r0[x - 1] : 0.f;
        float hi = (x < LBF - 1) ? m2 * r2[x + 1] : 0.f;
        o[x] = lo + r1[x] + hi;
    }
}

// ---------------- fuse pass B + masked softmax + compaction + self-pad --------
__global__ __launch_bounds__(256)
void fuseB_softmax(const float* __restrict__ FT1, const int* __restrict__ pos,
                   _Float16* __restrict__ attTc_g) {
    int j = blockIdx.x, bb = blockIdx.y;
    int tid = threadIdx.x;
    const float* F = FT1 + (long)bb * LBF * LBF;
    _Float16* orow = attTc_g + ((long)bb * LBF + j) * LDK2;
    int Pj = (j % 48) * 48 + j / 48;
    long roff[3]; bool jok[3];
#pragma unroll
    for (int t = 0; t < 3; t++) {
        int j2 = Pj + t - 1;
        jok[t] = (unsigned)j2 < (unsigned)LBF;
        int jc = jok[t] ? j2 : 0;
        roff[t] = (long)((jc % 48) * 48 + jc / 48) * LBF;
    }
    float v[9]; int ps[9];
    float mx = -1e30f;
#pragma unroll
    for (int u = 0; u < 9; u++) {
        int x = tid + u * 256;
        int sp = pos[x];
        ps[u] = sp;
        float xv = 0.f;
        if (sp >= 0) {
            int a = x / 48, b = x - a * 48;
            int Px = b * 48 + a;
            float acc = 0.f;
#pragma unroll
            for (int t = 0; t < 3; t++) {
                int d2 = t - 1;
                int uu = Px + d2;
                if (jok[t] && (unsigned)uu < (unsigned)LBF) {
                    int ad = a + d2;
                    int c = ((unsigned)ad < 48u) ? (x + 48 * d2)
                          : (ad == 48 ? (b + 1) : (2255 + b));
                    acc += F[roff[t] + c];
                }
            }
            xv = acc * 10.f;
        }
        v[u] = xv;
        mx = fmaxf(mx, xv);
    }
    for (int m = 32; m; m >>= 1) mx = fmaxf(mx, __shfl_xor(mx, m));
    __shared__ float sh[4], sh2[4];
    if ((tid & 63) == 0) sh[tid >> 6] = mx;
    __syncthreads();
    mx = fmaxf(fmaxf(sh[0], sh[1]), fmaxf(sh[2], sh[3]));
    float sum = 0.f;
#pragma unroll
    for (int u = 0; u < 9; u++) { v[u] = __expf(v[u] - mx); sum += v[u]; }
    for (int m = 32; m; m >>= 1) sum += __shfl_xor(sum, m);
    if ((tid & 63) == 0) sh2[tid >> 6] = sum;
    __syncthreads();
    sum = sh2[0] + sh2[1] + sh2[2] + sh2[3];
    float inv = 1.f / sum;
#pragma unroll
    for (int u = 0; u < 9; u++) {
        if (ps[u] >= 0) orow[ps[u]] = (_Float16)(v[u] * inv);
    }
    // self-pad: zero columns [Kc, Kpad)
    int kc = dec_kc(pos[2303]);
    int kp = (kc + 63) & ~63;
    if (tid < kp - kc) orow[kc + tid] = (_Float16)0.f;
}

// ---------------- scatter from MT[n][p]: coalesced transposed-conv gather -----
__global__ void scatter_out(const float* __restrict__ MT_, float* __restrict__ out) {
    int yx = blockIdx.x * 256 + threadIdx.x;  // [0, 9216)
    int c = blockIdx.y, b = blockIdx.z;
    int y = yx / 96, x = yx % 96;
    const float* Mb = MT_ + (long)b * 2048 * LBF;
    float s = 0.f;
    for (int uu = (y + 1) & 1; uu < 4; uu += 2) {
        int fi = (y + 1 - uu) >> 1;
        if ((unsigned)fi >= 48u) continue;
        for (int vv = (x + 1) & 1; vv < 4; vv += 2) {
            int fj = (x + 1 - vv) >> 1;
            if ((unsigned)fj >= 48u) continue;
            s += Mb[(long)(c * 16 + uu * 4 + vv) * LBF + fi * 48 + fj];
        }
    }
    out[(((long)b * 128 + c) * 96 + y) * 96 + x] = 0.25f * s;
}

extern "C" void kernel_launch(void* const* d_in, const int* in_sizes, int n_in,
                              void* d_out, int out_size, void* d_ws, size_t ws_size,
                              hipStream_t stream) {
    const float* f    = (const float*)d_in[0];
    const float* bsrc = (const float*)d_in[1];
    const float* mask = (const float*)d_in[2];
    float* out = (float*)d_out;

    // workspace regions (reuse; NEED == 207627264 == proven-available):
    //  ST   [0, 85MB)          -> MT (75.5MB) after fuse
    //  fp/wn [85, 127.4MB)     -> attTc
    //  Wtc  [127.4, 165.2MB)
    //  ds(9.4MB)/FT1x2 [165.2, 207.62MB)   (ds dead after GEMM1 inputs built)
    //  pos' [207.618048, +9216)
    char* ws = (char*)d_ws;
    const size_t offR1  = 84934656;
    const size_t offWn  = offR1 + 21233664;
    const size_t offWtc = offR1 + 42467328;
    const size_t offFT1 = offWtc + 37748736;          // 165150720
    const size_t offPos = offFT1 + 2ul * 21233664;    // 207618048
    const size_t NEED   = offPos + 9216;              // 207627264
    if (ws_size < NEED) return;  // visible failure, no OOB writes

    float*    ST    = (float*)(ws + 0);
    float*    MT    = (float*)(ws + 0);
    _Float16* fp    = (_Float16*)(ws + offR1);
    _Float16* wn    = (_Float16*)(ws + offWn);
    _Float16* attTc = (_Float16*)(ws + offR1);
    _Float16* Wtc   = (_Float16*)(ws + offWtc);
    float*    ds    = (float*)(ws + offFT1);          // 2*4*128*2304*4 = 9.4 MB
    float*    FT1   = (float*)(ws + offFT1);
    int*      pos   = (int*)(ws + offPos);

    stage_ds<<<dim3(9216), 256, 0, stream>>>(f, bsrc, ds);
    scan_mm<<<dim3(1), 256, 0, stream>>>(mask, pos);
    prep_fp<<<dim3(9, 2304, 4), 128, 0, stream>>>(ds, fp);
    prep_wn<<<dim3(2304, 4), 128, 0, stream>>>(ds, wn);
    prep_wtc<<<dim3(9, 2048, 4), 256, 0, stream>>>(bsrc, pos, Wtc);

    // GEMM1: ST[j,i] = sum_k fp[j,k] * wn[i,k]  (static K=1152)
    gemm_nt64<<<dim3(18, 18, 4), 256, 0, stream>>>(fp, wn, ST, 2304, 2304, K1, 0,
        nullptr, K1, (long)2304 * K1, (long)2304 * K1, (long)2304 * 2304);

    for (int g = 0; g < 2; g++) {
        fuseA<<<dim3(LBF, 2), 256, 0, stream>>>(ST + (long)g * 2 * LBF * LBF, FT1);
        fuseB_softmax<<<dim3(LBF, 2), 256, 0, stream>>>(FT1, pos,
            attTc + (long)g * 2 * LBF * LDK2);
    }

    // GEMM2 transposed output, R4 block-order: x sweeps Wtc (A), y pins attTc (B)
    gemm_nt64<<<dim3(16, 18, 4), 256, 0, stream>>>(Wtc, attTc, MT, 2048, 2304, LDK2, 1,
        pos + 2303, 0, (long)2048 * LDK2, (long)2304 * LDK2, (long)2048 * 2304);

    scatter_out<<<dim3(36, 128, 4), 256, 0, stream>>>(MT, out);
}